// Round 1
// baseline (1033.979 us; speedup 1.0000x reference)
//
#include <hip/hip_runtime.h>
#include <hip/hip_bf16.h>
#include <math.h>

#define B_    32
#define T_    1024
#define D_    384
#define MAXF  4608
#define NTOK  (B_ * T_)          // 32768
#define EPS_  1e-5f

// ---------------------------------------------------------------------------
// conv1d(K=3, SAME) + bias + ReLU as a tiled fp32 GEMM.
// Y[m, f] = relu( sum_{ktap=0..2} sum_{c=0..383} Xs[m,ktap,c] * W[ktap,c,f] + bias[f] )
// Xs[m,ktap,c] = X[m + ktap - 1, c] if (m%1024)+ktap-1 in [0,1024) else 0.
// Tile: 128x128 output, 256 threads, 8x8 accumulators/thread, BK=16.
// K-chunks (16) divide 384 exactly, so each chunk is within one ktap.
// ---------------------------------------------------------------------------
__global__ __launch_bounds__(256)
void conv_relu_kernel(const float* __restrict__ X, const float* __restrict__ W,
                      const float* __restrict__ bias, float* __restrict__ Y)
{
    __shared__ float As[16][128];   // As[k][m]  (A transposed)
    __shared__ float Bs[16][128];   // Bs[k][f]

    const int row0 = blockIdx.x * 128;
    const int col0 = blockIdx.y * 128;
    const int tid  = threadIdx.x;
    const int ty   = tid >> 4;            // 0..15
    const int tx   = tid & 15;            // 0..15

    const int mA = tid >> 2;              // 0..63   (A-load row within tile)
    const int c4 = (tid & 3) << 2;        // 0,4,8,12 (A-load col group)
    const int cB = tid >> 5;              // 0..7    (B-load row)
    const int f4 = (tid & 31) << 2;       // 0..124  (B-load col group)

    float acc[8][8];
    #pragma unroll
    for (int i = 0; i < 8; ++i)
        #pragma unroll
        for (int j = 0; j < 8; ++j) acc[i][j] = 0.f;

    for (int ktap = 0; ktap < 3; ++ktap) {
        for (int cc = 0; cc < 24; ++cc) {
            const int c0 = cc << 4;

            // ---- global loads (registers) ----
            const int tok0 = row0 + mA;
            const int tok1 = tok0 + 64;
            float4 a0, a1;
            {
                int t = tok0 & (T_ - 1);
                int st = t + ktap - 1;
                if (st < 0 || st >= T_) a0 = make_float4(0.f, 0.f, 0.f, 0.f);
                else a0 = *(const float4*)(X + (size_t)(tok0 + ktap - 1) * D_ + c0 + c4);
            }
            {
                int t = tok1 & (T_ - 1);
                int st = t + ktap - 1;
                if (st < 0 || st >= T_) a1 = make_float4(0.f, 0.f, 0.f, 0.f);
                else a1 = *(const float4*)(X + (size_t)(tok1 + ktap - 1) * D_ + c0 + c4);
            }
            const float* wb = W + ((size_t)ktap * D_ + c0) * D_ + col0;
            float4 b0 = *(const float4*)(wb + (size_t)cB * D_ + f4);
            float4 b1 = *(const float4*)(wb + (size_t)(cB + 8) * D_ + f4);

            __syncthreads();   // protect previous chunk's LDS reads
            As[c4 + 0][mA]      = a0.x;
            As[c4 + 1][mA]      = a0.y;
            As[c4 + 2][mA]      = a0.z;
            As[c4 + 3][mA]      = a0.w;
            As[c4 + 0][mA + 64] = a1.x;
            As[c4 + 1][mA + 64] = a1.y;
            As[c4 + 2][mA + 64] = a1.z;
            As[c4 + 3][mA + 64] = a1.w;
            *(float4*)&Bs[cB][f4]     = b0;
            *(float4*)&Bs[cB + 8][f4] = b1;
            __syncthreads();

            // ---- 16-deep FMA inner loop ----
            #pragma unroll
            for (int kk = 0; kk < 16; ++kk) {
                float4 x0 = *(const float4*)&As[kk][(ty << 2)];
                float4 x1 = *(const float4*)&As[kk][(ty << 2) + 64];
                float4 y0 = *(const float4*)&Bs[kk][(tx << 2)];
                float4 y1 = *(const float4*)&Bs[kk][(tx << 2) + 64];
                float ax[8] = {x0.x, x0.y, x0.z, x0.w, x1.x, x1.y, x1.z, x1.w};
                float by[8] = {y0.x, y0.y, y0.z, y0.w, y1.x, y1.y, y1.z, y1.w};
                #pragma unroll
                for (int i = 0; i < 8; ++i)
                    #pragma unroll
                    for (int j = 0; j < 8; ++j)
                        acc[i][j] = fmaf(ax[i], by[j], acc[i][j]);
            }
        }
    }

    // ---- epilogue: +bias, ReLU, store ----
    const float* bp = bias + col0;
    #pragma unroll
    for (int ih = 0; ih < 2; ++ih) {
        #pragma unroll
        for (int i = 0; i < 4; ++i) {
            const int m = row0 + ih * 64 + (ty << 2) + i;
            float* yr = Y + (size_t)m * D_ + col0;
            #pragma unroll
            for (int jh = 0; jh < 2; ++jh) {
                const int jc = jh * 64 + (tx << 2);
                float4 r;
                r.x = fmaxf(acc[ih * 4 + i][jh * 4 + 0] + bp[jc + 0], 0.f);
                r.y = fmaxf(acc[ih * 4 + i][jh * 4 + 1] + bp[jc + 1], 0.f);
                r.z = fmaxf(acc[ih * 4 + i][jh * 4 + 2] + bp[jc + 2], 0.f);
                r.w = fmaxf(acc[ih * 4 + i][jh * 4 + 3] + bp[jc + 3], 0.f);
                *(float4*)(yr + jc) = r;
            }
        }
    }
}

// ---------------------------------------------------------------------------
// LayerNorm over last dim (384). One wave per row, 6 floats per lane.
// ---------------------------------------------------------------------------
__global__ __launch_bounds__(256)
void ln_kernel(const float* __restrict__ in, const float* __restrict__ g,
               const float* __restrict__ bta, float* __restrict__ out)
{
    const int gw   = (int)((blockIdx.x * blockDim.x + threadIdx.x) >> 6);
    const int lane = threadIdx.x & 63;
    if (gw >= NTOK) return;
    const float* row = in + (size_t)gw * D_;

    float v[6];
    float s = 0.f;
    #pragma unroll
    for (int j = 0; j < 3; ++j) {
        float2 t = *(const float2*)(row + ((j << 6) + lane) * 2);
        v[2 * j] = t.x; v[2 * j + 1] = t.y;
        s += t.x + t.y;
    }
    #pragma unroll
    for (int off = 32; off >= 1; off >>= 1) s += __shfl_xor(s, off);
    const float mean = s / 384.f;

    float q = 0.f;
    #pragma unroll
    for (int k = 0; k < 6; ++k) { float d = v[k] - mean; q += d * d; }
    #pragma unroll
    for (int off = 32; off >= 1; off >>= 1) q += __shfl_xor(q, off);
    const float rstd = 1.0f / sqrtf(q / 384.f + EPS_);

    float* orow = out + (size_t)gw * D_;
    #pragma unroll
    for (int j = 0; j < 3; ++j) {
        const int c = ((j << 6) + lane) * 2;
        float2 o;
        o.x = (v[2 * j]     - mean) * rstd * g[c]     + bta[c];
        o.y = (v[2 * j + 1] - mean) * rstd * g[c + 1] + bta[c + 1];
        *(float2*)(orow + c) = o;
    }
}

// ---------------------------------------------------------------------------
// LayerNorm + final linear (384 -> 1): writes log_pred[row].
// ---------------------------------------------------------------------------
__global__ __launch_bounds__(256)
void ln_linear_kernel(const float* __restrict__ in, const float* __restrict__ g,
                      const float* __restrict__ bta, const float* __restrict__ lw,
                      const float* __restrict__ lb, float* __restrict__ lp)
{
    const int gw   = (int)((blockIdx.x * blockDim.x + threadIdx.x) >> 6);
    const int lane = threadIdx.x & 63;
    if (gw >= NTOK) return;
    const float* row = in + (size_t)gw * D_;

    float v[6];
    float s = 0.f;
    #pragma unroll
    for (int j = 0; j < 3; ++j) {
        float2 t = *(const float2*)(row + ((j << 6) + lane) * 2);
        v[2 * j] = t.x; v[2 * j + 1] = t.y;
        s += t.x + t.y;
    }
    #pragma unroll
    for (int off = 32; off >= 1; off >>= 1) s += __shfl_xor(s, off);
    const float mean = s / 384.f;

    float q = 0.f;
    #pragma unroll
    for (int k = 0; k < 6; ++k) { float d = v[k] - mean; q += d * d; }
    #pragma unroll
    for (int off = 32; off >= 1; off >>= 1) q += __shfl_xor(q, off);
    const float rstd = 1.0f / sqrtf(q / 384.f + EPS_);

    float p = 0.f;
    #pragma unroll
    for (int j = 0; j < 3; ++j) {
        const int c = ((j << 6) + lane) * 2;
        p += ((v[2 * j]     - mean) * rstd * g[c]     + bta[c])     * lw[c];
        p += ((v[2 * j + 1] - mean) * rstd * g[c + 1] + bta[c + 1]) * lw[c + 1];
    }
    #pragma unroll
    for (int off = 32; off >= 1; off >>= 1) p += __shfl_xor(p, off);
    if (lane == 0) lp[gw] = p + lb[0];
}

// ---------------------------------------------------------------------------
// Per-batch: dur = rint(exp(log_pred)); inclusive cumsum over T=1024.
// One wave per batch, 16 elements per lane.
// ---------------------------------------------------------------------------
__global__ __launch_bounds__(64)
void cumsum_kernel(const float* __restrict__ lp, int* __restrict__ cum)
{
    const int b    = blockIdx.x;
    const int lane = threadIdx.x;
    const int base = b * T_;

    int vals[16];
    int s = 0;
    #pragma unroll
    for (int j = 0; j < 16; ++j) {
        float e = expf(lp[base + lane * 16 + j]);
        int d = (int)rintf(e);          // RTNE == jnp.round half-to-even
        vals[j] = d;
        s += d;
    }
    // inclusive wave scan of per-lane sums
    int incl = s;
    #pragma unroll
    for (int off = 1; off < 64; off <<= 1) {
        int n = __shfl_up(incl, off);
        if (lane >= off) incl += n;
    }
    int run = incl - s;   // exclusive prefix
    #pragma unroll
    for (int j = 0; j < 16; ++j) {
        run += vals[j];
        cum[base + lane * 16 + j] = run;
    }
}

// ---------------------------------------------------------------------------
// Length regulation: for each (b, frame): idx = upper_bound(cum, frame),
// clipped to T-1; out = x[b, idx, :] * (frame < cum[T-1]).
// One wave per output frame row; coalesced float2 copies.
// ---------------------------------------------------------------------------
__global__ __launch_bounds__(256)
void gather_kernel(const float* __restrict__ X, const int* __restrict__ cum,
                   float* __restrict__ out)
{
    const int gw   = (int)((blockIdx.x * blockDim.x + threadIdx.x) >> 6);
    const int lane = threadIdx.x & 63;
    const int b    = gw / MAXF;
    const int fr   = gw % MAXF;

    const int* c = cum + b * T_;
    const int total = c[T_ - 1];

    // upper_bound: first pos with c[pos] > fr
    int lo = 0, hi = T_;
    while (lo < hi) {
        int mid = (lo + hi) >> 1;
        if (c[mid] <= fr) lo = mid + 1; else hi = mid;
    }
    const int idx = min(lo, T_ - 1);
    const float mask = (fr < total) ? 1.0f : 0.0f;

    const float* src = X + ((size_t)b * T_ + idx) * D_;
    float* dst = out + (size_t)gw * D_;
    #pragma unroll
    for (int j = 0; j < 3; ++j) {
        const int c2 = ((j << 6) + lane) * 2;
        float2 t = *(const float2*)(src + c2);
        t.x *= mask; t.y *= mask;
        *(float2*)(dst + c2) = t;
    }
}

// ---------------------------------------------------------------------------
extern "C" void kernel_launch(void* const* d_in, const int* in_sizes, int n_in,
                              void* d_out, int out_size, void* d_ws, size_t ws_size,
                              hipStream_t stream)
{
    const float* x   = (const float*)d_in[0];
    const float* w1  = (const float*)d_in[1];
    const float* b1  = (const float*)d_in[2];
    const float* g1  = (const float*)d_in[3];
    const float* be1 = (const float*)d_in[4];
    const float* w2  = (const float*)d_in[5];
    const float* b2  = (const float*)d_in[6];
    const float* g2  = (const float*)d_in[7];
    const float* be2 = (const float*)d_in[8];
    const float* lw  = (const float*)d_in[9];
    const float* lb  = (const float*)d_in[10];

    float* out  = (float*)d_out;
    // Scratch lives in the d_out arena (fully overwritten by gather at the end):
    float* tmpA = out;                              // [NTOK, 384] conv outputs
    float* h1   = out + (size_t)NTOK * D_;          // [NTOK, 384] after LN1
    float* lp   = out + (size_t)B_ * MAXF * D_;     // [B, T] log_pred (real output #1)
    int*   cum  = (int*)d_ws;                       // [B, T] cumulative durations

    dim3 cgrid(NTOK / 128, 3);

    // conv1 + relu  -> tmpA
    conv_relu_kernel<<<cgrid, 256, 0, stream>>>(x, w1, b1, tmpA);
    // LN1 -> h1
    ln_kernel<<<NTOK / 4, 256, 0, stream>>>(tmpA, g1, be1, h1);
    // conv2 + relu -> tmpA (reuse)
    conv_relu_kernel<<<cgrid, 256, 0, stream>>>(h1, w2, b2, tmpA);
    // LN2 + linear -> lp
    ln_linear_kernel<<<NTOK / 4, 256, 0, stream>>>(tmpA, g2, be2, lw, lb, lp);
    // durations + cumsum -> cum
    cumsum_kernel<<<B_, 64, 0, stream>>>(lp, cum);
    // length regulation -> out[0 : B*MAXF*D]
    gather_kernel<<<(B_ * MAXF) / 4, 256, 0, stream>>>(x, cum, out);
}

// Round 2
// 813.433 us; speedup vs baseline: 1.2711x; 1.2711x over previous
//
#include <hip/hip_runtime.h>
#include <hip/hip_bf16.h>
#include <math.h>

#define B_    32
#define T_    1024
#define D_    384
#define MAXF  4608
#define NTOK  (B_ * T_)          // 32768
#define TPAD  1026               // per-batch padded token rows (zero row each side)
#define NPROW (B_ * TPAD)        // 32832 padded rows
#define EPS_  1e-5f

typedef __bf16 bf16x8 __attribute__((ext_vector_type(8)));
typedef float  f32x4  __attribute__((ext_vector_type(4)));

// ---- fp32 <-> bf16 (RTNE) on raw bits ------------------------------------
__device__ __forceinline__ ushort f2bf(float f) {
    uint x = __float_as_uint(f);
    uint r = (x + 0x7FFFu + ((x >> 16) & 1u)) >> 16;
    return (ushort)r;
}
__device__ __forceinline__ float bf2f(ushort u) {
    return __uint_as_float(((uint)u) << 16);
}
__device__ __forceinline__ void split3(float v, ushort& a, ushort& b, ushort& c) {
    a = f2bf(v);        float r1 = v  - bf2f(a);
    b = f2bf(r1);       float r2 = r1 - bf2f(b);
    c = f2bf(r2);
}

__device__ __forceinline__ void gll16(const ushort* src, ushort* lds_dst) {
    __builtin_amdgcn_global_load_lds(
        (const __attribute__((address_space(1))) void*)src,
        (__attribute__((address_space(3))) void*)lds_dst, 16, 0, 0);
}

// ---------------------------------------------------------------------------
// split_x: x fp32 [B,T,D] -> 3 bf16 planes [B][TPAD][D], rows 0/1025 zeroed.
// One wave per padded row.
// ---------------------------------------------------------------------------
__global__ __launch_bounds__(256)
void split_x_kernel(const float* __restrict__ x,
                    ushort* __restrict__ P0, ushort* __restrict__ P1, ushort* __restrict__ P2)
{
    const int row  = (int)((blockIdx.x * blockDim.x + threadIdx.x) >> 6);
    const int lane = threadIdx.x & 63;
    if (row >= NPROW) return;
    const int b = row / TPAD, tk = row % TPAD;

    uint* p0 = (uint*)P0 + (size_t)row * 192;
    uint* p1 = (uint*)P1 + (size_t)row * 192;
    uint* p2 = (uint*)P2 + (size_t)row * 192;

    if (tk == 0 || tk == TPAD - 1) {
        #pragma unroll
        for (int j = 0; j < 3; ++j) {
            p0[j * 64 + lane] = 0u; p1[j * 64 + lane] = 0u; p2[j * 64 + lane] = 0u;
        }
        return;
    }
    const float* src = x + ((size_t)b * T_ + (tk - 1)) * D_;
    #pragma unroll
    for (int j = 0; j < 3; ++j) {
        float2 t = *(const float2*)(src + j * 128 + lane * 2);
        ushort a0, b0, c0, a1, b1, c1;
        split3(t.x, a0, b0, c0);
        split3(t.y, a1, b1, c1);
        p0[j * 64 + lane] = (uint)a0 | ((uint)a1 << 16);
        p1[j * 64 + lane] = (uint)b0 | ((uint)b1 << 16);
        p2[j * 64 + lane] = (uint)c0 | ((uint)c1 << 16);
    }
}

// ---------------------------------------------------------------------------
// ln_split: LN(conv1_out) -> 3 bf16 padded planes (conv2's A operand).
// ---------------------------------------------------------------------------
__global__ __launch_bounds__(256)
void ln_split_kernel(const float* __restrict__ in, const float* __restrict__ g,
                     const float* __restrict__ bta,
                     ushort* __restrict__ P0, ushort* __restrict__ P1, ushort* __restrict__ P2)
{
    const int row  = (int)((blockIdx.x * blockDim.x + threadIdx.x) >> 6);
    const int lane = threadIdx.x & 63;
    if (row >= NPROW) return;
    const int b = row / TPAD, tk = row % TPAD;

    uint* p0 = (uint*)P0 + (size_t)row * 192;
    uint* p1 = (uint*)P1 + (size_t)row * 192;
    uint* p2 = (uint*)P2 + (size_t)row * 192;

    if (tk == 0 || tk == TPAD - 1) {
        #pragma unroll
        for (int j = 0; j < 3; ++j) {
            p0[j * 64 + lane] = 0u; p1[j * 64 + lane] = 0u; p2[j * 64 + lane] = 0u;
        }
        return;
    }
    const float* src = in + ((size_t)b * T_ + (tk - 1)) * D_;

    float v[6];
    float s = 0.f;
    #pragma unroll
    for (int j = 0; j < 3; ++j) {
        float2 t = *(const float2*)(src + j * 128 + lane * 2);
        v[2 * j] = t.x; v[2 * j + 1] = t.y;
        s += t.x + t.y;
    }
    #pragma unroll
    for (int off = 32; off >= 1; off >>= 1) s += __shfl_xor(s, off);
    const float mean = s / 384.f;
    float q = 0.f;
    #pragma unroll
    for (int k = 0; k < 6; ++k) { float d = v[k] - mean; q += d * d; }
    #pragma unroll
    for (int off = 32; off >= 1; off >>= 1) q += __shfl_xor(q, off);
    const float rstd = 1.0f / sqrtf(q / 384.f + EPS_);

    #pragma unroll
    for (int j = 0; j < 3; ++j) {
        const int c = j * 128 + lane * 2;
        float o0 = (v[2 * j]     - mean) * rstd * g[c]     + bta[c];
        float o1 = (v[2 * j + 1] - mean) * rstd * g[c + 1] + bta[c + 1];
        ushort a0, b0, c0, a1, b1, c1;
        split3(o0, a0, b0, c0);
        split3(o1, a1, b1, c1);
        p0[j * 64 + lane] = (uint)a0 | ((uint)a1 << 16);
        p1[j * 64 + lane] = (uint)b0 | ((uint)b1 << 16);
        p2[j * 64 + lane] = (uint)c0 | ((uint)c1 << 16);
    }
}

// ---------------------------------------------------------------------------
// split_w: w fp32 [K=3, Cin=384, Cout=384] -> 3 bf16 TRANSPOSED planes
// wT[p][n][kf] with kf = t*384 + c, row stride 1152.  (B operand, n-major)
// ---------------------------------------------------------------------------
__global__ __launch_bounds__(256)
void split_w_kernel(const float* __restrict__ w,
                    ushort* __restrict__ P0, ushort* __restrict__ P1, ushort* __restrict__ P2)
{
    const int p = (int)(blockIdx.x * blockDim.x + threadIdx.x);   // pair index
    if (p >= 384 * 576) return;
    const int n = p / 576, kp = p % 576;
    const int kf0 = kp * 2;
    float w0 = w[(size_t)kf0 * 384 + n];
    float w1 = w[(size_t)(kf0 + 1) * 384 + n];
    ushort a0, b0, c0, a1, b1, c1;
    split3(w0, a0, b0, c0);
    split3(w1, a1, b1, c1);
    ((uint*)P0)[(size_t)n * 576 + kp] = (uint)a0 | ((uint)a1 << 16);
    ((uint*)P1)[(size_t)n * 576 + kp] = (uint)b0 | ((uint)b1 << 16);
    ((uint*)P2)[(size_t)n * 576 + kp] = (uint)c0 | ((uint)c1 << 16);
}

// ---------------------------------------------------------------------------
// conv as bf16x6 MFMA GEMM.  C[m,n] = relu( sum_ext A_ext[m,k] B_ext[k,n] + bias[n] )
// A planes: padded [B][TPAD][384] bf16 (shift by tap t handled via +t row offset)
// B planes: transposed [384 n][1152 kf] bf16
// Tile 128x128, 4 waves (64x64 each), BK=64, 16x16x32 MFMA.
// LDS linear; XOR chunk-swizzle applied on global SOURCE + fragment READ side.
// ---------------------------------------------------------------------------
__global__ __launch_bounds__(256)
void conv_mfma_kernel(const ushort* __restrict__ A0, const ushort* __restrict__ A1,
                      const ushort* __restrict__ A2,
                      const ushort* __restrict__ B0, const ushort* __restrict__ B1,
                      const ushort* __restrict__ B2,
                      const float* __restrict__ bias, float* __restrict__ Y)
{
    __shared__ ushort As[128 * 64];   // [128 rows][64 k] bf16, rows 128B
    __shared__ ushort Bs[128 * 64];   // [128 n-rows][64 k]

    const int row0 = blockIdx.x * 128;
    const int col0 = blockIdx.y * 128;
    const int b    = row0 >> 10;
    const int tk0  = row0 & (T_ - 1);

    const int tid  = threadIdx.x;
    const int wid  = tid >> 6;
    const int lane = tid & 63;
    const int wr   = wid >> 1, wc = wid & 1;     // wave sub-tile (64x64)

    // ---- staging lane constants (source pre-swizzle: chunk = (lane&7) ^ subrow)
    const int sr = lane >> 3;          // sub-row 0..7 inside an 8-row chunk
    const int sc = lane & 7;           // 16B chunk 0..7 in a 128B row
    const int csw8 = (sc ^ sr) * 8;    // swizzled chunk, in bf16 elements
    int aso[4], bso[4];
    #pragma unroll
    for (int jj = 0; jj < 4; ++jj) {
        const int rt = wid * 32 + jj * 8 + sr;
        aso[jj] = rt * 384  + csw8;
        bso[jj] = rt * 1152 + csw8;
    }

    // ---- fragment-read lane constants
    const int lm = lane & 15, gk = lane >> 4;
    const int cswr = ((gk ^ (lane & 7)) << 4);          // byte offset of swizzled chunk
    const int abase = (wr * 64 + lm) * 128 + cswr;      // + i*2048, ^ (ks<<6)
    const int bbase = (wc * 64 + lm) * 128 + cswr;

    f32x4 acc[4][4];
    #pragma unroll
    for (int i = 0; i < 4; ++i)
        #pragma unroll
        for (int j = 0; j < 4; ++j) { f32x4 z = {0.f, 0.f, 0.f, 0.f}; acc[i][j] = z; }

    constexpr int PA[6] = {0, 0, 1, 1, 0, 2};
    constexpr int PB[6] = {0, 1, 0, 1, 2, 0};

    const char* Asb = (const char*)As;
    const char* Bsb = (const char*)Bs;

    #pragma unroll
    for (int t = 0; t < 3; ++t) {
        #pragma unroll
        for (int u = 0; u < 6; ++u) {
            const ushort* Ap = (PA[u] == 0) ? A0 : (PA[u] == 1) ? A1 : A2;
            const ushort* Bp = (PB[u] == 0) ? B0 : (PB[u] == 1) ? B1 : B2;
            const size_t abase_g = ((size_t)(b * TPAD + tk0 + t)) * 384;
            const size_t bbase_g = (size_t)col0 * 1152 + t * 384;
            for (int kc = 0; kc < 6; ++kc) {
                const size_t ag = abase_g + kc * 64;
                const size_t bg = bbase_g + kc * 64;
                __syncthreads();                 // prior reads done before overwrite
                #pragma unroll
                for (int jj = 0; jj < 4; ++jj) {
                    gll16(Ap + ag + aso[jj], As + (wid * 4 + jj) * 512);
                    gll16(Bp + bg + bso[jj], Bs + (wid * 4 + jj) * 512);
                }
                __syncthreads();                 // vmcnt drain + barrier

                #pragma unroll
                for (int ks = 0; ks < 2; ++ks) {
                    bf16x8 av[4], bv[4];
                    #pragma unroll
                    for (int i = 0; i < 4; ++i)
                        av[i] = *(const bf16x8*)(Asb + ((abase + i * 2048) ^ (ks << 6)));
                    #pragma unroll
                    for (int j = 0; j < 4; ++j)
                        bv[j] = *(const bf16x8*)(Bsb + ((bbase + j * 2048) ^ (ks << 6)));
                    #pragma unroll
                    for (int i = 0; i < 4; ++i)
                        #pragma unroll
                        for (int j = 0; j < 4; ++j)
                            acc[i][j] = __builtin_amdgcn_mfma_f32_16x16x32_bf16(
                                av[i], bv[j], acc[i][j], 0, 0, 0);
                }
            }
        }
    }

    // ---- epilogue: +bias, relu, fp32 store
    float bj[4];
    #pragma unroll
    for (int j = 0; j < 4; ++j) bj[j] = bias[col0 + wc * 64 + j * 16 + lm];
    const int r4 = gk * 4;
    #pragma unroll
    for (int i = 0; i < 4; ++i) {
        #pragma unroll
        for (int q = 0; q < 4; ++q) {
            const size_t row = (size_t)row0 + wr * 64 + i * 16 + r4 + q;
            float* yr = Y + row * D_ + col0 + wc * 64 + lm;
            #pragma unroll
            for (int j = 0; j < 4; ++j)
                yr[j * 16] = fmaxf(acc[i][j][q] + bj[j], 0.f);
        }
    }
}

// ---------------------------------------------------------------------------
// LayerNorm + final linear (384 -> 1): writes log_pred[row].  (fp32, unchanged)
// ---------------------------------------------------------------------------
__global__ __launch_bounds__(256)
void ln_linear_kernel(const float* __restrict__ in, const float* __restrict__ g,
                      const float* __restrict__ bta, const float* __restrict__ lw,
                      const float* __restrict__ lb, float* __restrict__ lp)
{
    const int gw   = (int)((blockIdx.x * blockDim.x + threadIdx.x) >> 6);
    const int lane = threadIdx.x & 63;
    if (gw >= NTOK) return;
    const float* row = in + (size_t)gw * D_;

    float v[6];
    float s = 0.f;
    #pragma unroll
    for (int j = 0; j < 3; ++j) {
        float2 t = *(const float2*)(row + ((j << 6) + lane) * 2);
        v[2 * j] = t.x; v[2 * j + 1] = t.y;
        s += t.x + t.y;
    }
    #pragma unroll
    for (int off = 32; off >= 1; off >>= 1) s += __shfl_xor(s, off);
    const float mean = s / 384.f;

    float q = 0.f;
    #pragma unroll
    for (int k = 0; k < 6; ++k) { float d = v[k] - mean; q += d * d; }
    #pragma unroll
    for (int off = 32; off >= 1; off >>= 1) q += __shfl_xor(q, off);
    const float rstd = 1.0f / sqrtf(q / 384.f + EPS_);

    float p = 0.f;
    #pragma unroll
    for (int j = 0; j < 3; ++j) {
        const int c = ((j << 6) + lane) * 2;
        p += ((v[2 * j]     - mean) * rstd * g[c]     + bta[c])     * lw[c];
        p += ((v[2 * j + 1] - mean) * rstd * g[c + 1] + bta[c + 1]) * lw[c + 1];
    }
    #pragma unroll
    for (int off = 32; off >= 1; off >>= 1) p += __shfl_xor(p, off);
    if (lane == 0) lp[gw] = p + lb[0];
}

// ---------------------------------------------------------------------------
__global__ __launch_bounds__(64)
void cumsum_kernel(const float* __restrict__ lp, int* __restrict__ cum)
{
    const int b    = blockIdx.x;
    const int lane = threadIdx.x;
    const int base = b * T_;

    int vals[16];
    int s = 0;
    #pragma unroll
    for (int j = 0; j < 16; ++j) {
        float e = expf(lp[base + lane * 16 + j]);
        int d = (int)rintf(e);
        vals[j] = d;
        s += d;
    }
    int incl = s;
    #pragma unroll
    for (int off = 1; off < 64; off <<= 1) {
        int n = __shfl_up(incl, off);
        if (lane >= off) incl += n;
    }
    int run = incl - s;
    #pragma unroll
    for (int j = 0; j < 16; ++j) {
        run += vals[j];
        cum[base + lane * 16 + j] = run;
    }
}

// ---------------------------------------------------------------------------
__global__ __launch_bounds__(256)
void gather_kernel(const float* __restrict__ X, const int* __restrict__ cum,
                   float* __restrict__ out)
{
    const int gw   = (int)((blockIdx.x * blockDim.x + threadIdx.x) >> 6);
    const int lane = threadIdx.x & 63;
    const int b    = gw / MAXF;
    const int fr   = gw % MAXF;

    const int* c = cum + b * T_;
    const int total = c[T_ - 1];

    int lo = 0, hi = T_;
    while (lo < hi) {
        int mid = (lo + hi) >> 1;
        if (c[mid] <= fr) lo = mid + 1; else hi = mid;
    }
    const int idx = min(lo, T_ - 1);
    const float mask = (fr < total) ? 1.0f : 0.0f;

    const float* src = X + ((size_t)b * T_ + idx) * D_;
    float* dst = out + (size_t)gw * D_;
    #pragma unroll
    for (int j = 0; j < 3; ++j) {
        const int c2 = ((j << 6) + lane) * 2;
        float2 t = *(const float2*)(src + c2);
        t.x *= mask; t.y *= mask;
        *(float2*)(dst + c2) = t;
    }
}

// ---------------------------------------------------------------------------
extern "C" void kernel_launch(void* const* d_in, const int* in_sizes, int n_in,
                              void* d_out, int out_size, void* d_ws, size_t ws_size,
                              hipStream_t stream)
{
    const float* x   = (const float*)d_in[0];
    const float* w1  = (const float*)d_in[1];
    const float* b1  = (const float*)d_in[2];
    const float* g1  = (const float*)d_in[3];
    const float* be1 = (const float*)d_in[4];
    const float* w2  = (const float*)d_in[5];
    const float* b2  = (const float*)d_in[6];
    const float* g2  = (const float*)d_in[7];
    const float* be2 = (const float*)d_in[8];
    const float* lw  = (const float*)d_in[9];
    const float* lb  = (const float*)d_in[10];

    float* out = (float*)d_out;

    // ---- arena layout in d_out (all floats; gather overwrites [0, 56623104)):
    const size_t SPf = (size_t)NPROW * 192;          // padded bf16 plane, in float slots (6,303,744)
    ushort* X0 = (ushort*)(out);
    ushort* X1 = (ushort*)(out + SPf);
    ushort* X2 = (ushort*)(out + 2 * SPf);
    ushort* H0 = (ushort*)(out + 3 * SPf);
    ushort* H1 = (ushort*)(out + 4 * SPf);
    ushort* H2 = (ushort*)(out + 5 * SPf);
    float*  cvout = out + 6 * SPf;                   // conv fp32 out [NTOK,384] (12.58M floats)
    float*  wbase = cvout + (size_t)NTOK * D_;
    const size_t WPf = 384 * 576 / 2 * 2;            // 221,184 float slots per bf16 w-plane
    ushort* W0 = (ushort*)(wbase);
    ushort* W1p = (ushort*)(wbase + WPf);
    ushort* W2p = (ushort*)(wbase + 2 * WPf);
    ushort* V0 = (ushort*)(wbase + 3 * WPf);
    ushort* V1 = (ushort*)(wbase + 4 * WPf);
    ushort* V2 = (ushort*)(wbase + 5 * WPf);
    float*  lp  = out + (size_t)B_ * MAXF * D_;      // real output #2
    int*    cum = (int*)d_ws;

    dim3 cgrid(NTOK / 128, 3);

    split_x_kernel<<<(NPROW + 3) / 4, 256, 0, stream>>>(x, X0, X1, X2);
    split_w_kernel<<<(384 * 576 + 255) / 256, 256, 0, stream>>>(w1, W0, W1p, W2p);
    split_w_kernel<<<(384 * 576 + 255) / 256, 256, 0, stream>>>(w2, V0, V1, V2);

    conv_mfma_kernel<<<cgrid, 256, 0, stream>>>(X0, X1, X2, W0, W1p, W2p, b1, cvout);
    ln_split_kernel<<<(NPROW + 3) / 4, 256, 0, stream>>>(cvout, g1, be1, H0, H1, H2);
    conv_mfma_kernel<<<cgrid, 256, 0, stream>>>(H0, H1, H2, V0, V1, V2, b2, cvout);
    ln_linear_kernel<<<NTOK / 4, 256, 0, stream>>>(cvout, g2, be2, lw, lb, lp);
    cumsum_kernel<<<B_, 64, 0, stream>>>(lp, cum);
    gather_kernel<<<(B_ * MAXF) / 4, 256, 0, stream>>>(x, cum, out);
}